// Round 20
// baseline (130.286 us; speedup 1.0000x reference)
//
#include <hip/hip_runtime.h>
#include <hip/hip_bf16.h>
#include <math.h>

#define L 1024
typedef __hip_bfloat16 bf;
typedef __attribute__((ext_vector_type(8))) short short8v;
typedef __attribute__((ext_vector_type(4))) short short4v;

__device__ __forceinline__ float b2f(bf v) { return __bfloat162float(v); }
__device__ __forceinline__ bf f2b(float v) { return __float2bfloat16(v); }
__device__ __forceinline__ float bits2f(short s) {
  union { unsigned u; float f; } cv; cv.u = ((unsigned)(unsigned short)s) << 16; return cv.f;
}
union Pack4 { short4v v; unsigned short e[4]; };
union Pack8 { short8v v; unsigned short e[8]; };
__device__ __forceinline__ unsigned short f2bits(float v) {
  union { bf b; unsigned short u; } cv; cv.b = __float2bfloat16(v); return cv.u;
}

// ---- k_front: LDS x-tile + split conv (wave q: 8 d's) + in_proj quarters ---
__global__ __launch_bounds__(256, 2) void k_front(
    const float* __restrict__ x, const float* __restrict__ conv_w,
    const float* __restrict__ conv_b, const float* __restrict__ gamma,
    const float* __restrict__ beta, const float* __restrict__ mean,
    const float* __restrict__ var, const float* __restrict__ ipw,
    bf* __restrict__ xm, bf* __restrict__ z) {
  __shared__ float xs[64 * 65];    // 16.25 KB x-tile [c][l_local]
  __shared__ float hsh[64][34];    // 8.7 KB
  int t = threadIdx.x;
  int b = blockIdx.x >> 4;         // grid 1024 = 64 b x 16 ltiles
  int l0 = (blockIdx.x & 15) << 6;
  const float* xg = x + (size_t)b * 65536 + l0;
#pragma unroll
  for (int k = 0; k < 16; ++k) {
    int i = t + k * 256;           // [0,4096)
    int c = i >> 6, ll = i & 63;
    xs[c * 65 + ll] = xg[(size_t)c * L + ll];   // 1KB contiguous per wave
  }
  __syncthreads();
  int lq = t & 63;
  int q = __builtin_amdgcn_readfirstlane(t >> 6);  // wave idx, FORCED SGPR
  int l = l0 | lq;
  float hacc[8];
#pragma unroll
  for (int dd = 0; dd < 8; ++dd) hacc[dd] = conv_b[q * 8 + dd];
#pragma unroll
  for (int c4 = 0; c4 < 16; ++c4) {
    float x0 = xs[(c4 * 4 + 0) * 65 + lq];
    float x1 = xs[(c4 * 4 + 1) * 65 + lq];
    float x2 = xs[(c4 * 4 + 2) * 65 + lq];
    float x3 = xs[(c4 * 4 + 3) * 65 + lq];
#pragma unroll
    for (int dd = 0; dd < 8; ++dd) {
      const float* w = conv_w + (q * 8 + dd) * 64 + c4 * 4;  // s_load (uniform)
      hacc[dd] = fmaf(x0, w[0], fmaf(x1, w[1],
                 fmaf(x2, w[2], fmaf(x3, w[3], hacc[dd]))));
    }
  }
#pragma unroll
  for (int dd = 0; dd < 8; ++dd) {
    int d = q * 8 + dd;
    float sc = gamma[d] * rsqrtf(var[d] + 1e-5f);
    float acc = (hacc[dd] - mean[d]) * sc + beta[d];
    hsh[lq][d] = 0.5f * acc * (1.0f + erff(acc * 0.70710678118654752f));
  }
  __syncthreads();
  float h[32];
#pragma unroll
  for (int d = 0; d < 32; ++d) h[d] = hsh[lq][d];
  if (q < 2) {
    short8v* xr8 = (short8v*)(xm + ((size_t)b * 1024 + l) * 64) + q * 4;
#pragma unroll
    for (int j8 = 0; j8 < 4; ++j8) {
      Pack8 p;
#pragma unroll
      for (int e = 0; e < 8; ++e) {
        int j = q * 32 + j8 * 8 + e;
        float acc = 0.f;
#pragma unroll
        for (int d = 0; d < 32; ++d) acc = fmaf(h[d], ipw[j * 32 + d], acc);
        p.e[e] = f2bits(acc);
      }
      xr8[j8] = p.v;
    }
  } else {
    bf* zp = z + (size_t)b * 65536 + l;
#pragma unroll
    for (int jj = 0; jj < 32; ++jj) {
      int j = (q - 2) * 32 + jj;
      float acc = 0.f;
#pragma unroll
      for (int d = 0; d < 32; ++d) acc = fmaf(h[d], ipw[(j + 64) * 32 + d], acc);
      zp[(size_t)j * L] = f2b(acc);
    }
  }
}

// ---- k_mid: 4-wave split. Phase1: wave q -> conv1d+SiLU for 16 d's -> LDS.
// Phase2: w0 dt, w1 B01+C0, w2 B23+C1, w3 C23. All weight idx SGPR-uniform. --
__global__ __launch_bounds__(256, 2) void k_mid(
    const bf* __restrict__ xm, const float* __restrict__ c1w,
    const float* __restrict__ c1b, const float* __restrict__ xpw,
    const float* __restrict__ dtw, const float* __restrict__ dtbp,
    bf* __restrict__ u, bf* __restrict__ dt_o,
    bf* __restrict__ Bt, bf* __restrict__ Ct) {
  __shared__ float ush[64][65];    // 16.6 KB  [l_local][d]
  int t = threadIdx.x;
  int lq = t & 63;
  int q = __builtin_amdgcn_readfirstlane(t >> 6);   // wave idx, SGPR
  int b = blockIdx.x >> 4;         // grid 1024 = 64 b x 16 ltiles
  int l = ((blockIdx.x & 15) << 6) | lq;
  // phase 1: conv1d + silu for d in [16q, 16q+16)
  float um[16];
#pragma unroll
  for (int dd = 0; dd < 16; ++dd) um[dd] = c1b[q * 16 + dd];
#pragma unroll
  for (int k = 0; k < 4; ++k) {
    int lr = l - 3 + k;
    if (lr >= 0) {
      const short8v* row = (const short8v*)(xm + ((size_t)b * 1024 + lr) * 64 + q * 16);
      short8v v0 = row[0], v1 = row[1];
#pragma unroll
      for (int e = 0; e < 8; ++e) {
        um[e]     = fmaf(c1w[(q * 16 + e) * 4 + k],     bits2f(v0[e]), um[e]);
        um[8 + e] = fmaf(c1w[(q * 16 + 8 + e) * 4 + k], bits2f(v1[e]), um[8 + e]);
      }
    }
  }
  {
    bf* up = u + (size_t)b * 65536 + l;
#pragma unroll
    for (int dd = 0; dd < 16; ++dd) {
      float s = um[dd];
      s = s / (1.f + __expf(-s));           // silu
      ush[lq][q * 16 + dd] = s;
      up[(size_t)(q * 16 + dd) * L] = f2b(s);   // coalesced column stores
    }
  }
  __syncthreads();
  // phase 2: read full um, compute this wave's x_proj outputs
  float um64[64];
#pragma unroll
  for (int d = 0; d < 64; ++d) um64[d] = ush[lq][d];  // conflict-free
  int i = l & 31, c = l >> 5;
  size_t basei = ((size_t)b * 16384 + (size_t)i * 128 + c * 4) >> 2;
  if (q == 0) {
    float xd0 = 0.f, xd1 = 0.f;
#pragma unroll
    for (int d = 0; d < 64; ++d) {
      xd0 = fmaf(um64[d], xpw[d], xd0);
      xd1 = fmaf(um64[d], xpw[64 + d], xd1);
    }
    bf* dp = dt_o + (size_t)b * 65536 + l;
#pragma unroll
    for (int d = 0; d < 64; ++d) {
      float raw = fmaf(xd0, dtw[d * 2], fmaf(xd1, dtw[d * 2 + 1], dtbp[d]));
      float sp = fmaxf(raw, 0.f) + log1pf(__expf(-fabsf(raw)));
      dp[(size_t)d * L] = f2b(sp);
    }
  } else {
    // quad jobs per wave: {ptr, k-base, n4} x up to 3
    short4v* B4 = (short4v*)Bt;
    short4v* C4 = (short4v*)Ct;
#pragma unroll
    for (int job = 0; job < 3; ++job) {
      int kb, n4; short4v* dst;
      if (q == 1)      { if (job == 0) { dst = B4; kb = 2;  n4 = 0; }
                         else if (job == 1) { dst = B4; kb = 6;  n4 = 1; }
                         else { dst = C4; kb = 18; n4 = 0; } }
      else if (q == 2) { if (job == 0) { dst = B4; kb = 10; n4 = 2; }
                         else if (job == 1) { dst = B4; kb = 14; n4 = 3; }
                         else { dst = C4; kb = 22; n4 = 1; } }
      else             { if (job == 0) { dst = C4; kb = 26; n4 = 2; }
                         else if (job == 1) { dst = C4; kb = 30; n4 = 3; }
                         else break; }
      Pack4 p;
#pragma unroll
      for (int nn = 0; nn < 4; ++nn) {
        float acc = 0.f;
#pragma unroll
        for (int d = 0; d < 64; ++d) acc = fmaf(um64[d], xpw[(kb + nn) * 64 + d], acc);
        p.e[nn] = f2bits(acc);
      }
      dst[basei + (size_t)n4 * 1024] = p.v;
    }
  }
}

// ---- k_scan: single-sweep chunked scan, B/C in LDS (b64 quads), gate+pool --
__global__ __launch_bounds__(256, 2) void k_scan(
    const bf* __restrict__ u, const bf* __restrict__ dt,
    const bf* __restrict__ z, const bf* __restrict__ Bt,
    const bf* __restrict__ Ct, const float* __restrict__ A_log,
    const float* __restrict__ Dp, float* __restrict__ pooled64) {
  __shared__ bf Bsh[16384];
  __shared__ bf Csh[16384];
  int phys = blockIdx.x;      // 512 blocks
  int b = phys & 63;
  int dgrp = phys >> 6;
  int t = threadIdx.x;
  int d_local = t >> 5, c = t & 31;
  int d = dgrp * 8 + d_local;
  int g = b * 64 + d;

  {
    const short8v* Bg8 = (const short8v*)(Bt + (size_t)b * 16384);
    const short8v* Cg8 = (const short8v*)(Ct + (size_t)b * 16384);
    short8v* Bs8 = (short8v*)Bsh;
    short8v* Cs8 = (short8v*)Csh;
#pragma unroll
    for (int q = 0; q < 8; ++q) {
      Bs8[t + q * 256] = Bg8[t + q * 256];
      Cs8[t + q * 256] = Cg8[t + q * 256];
    }
  }
  __syncthreads();

  float An[16];
#pragma unroll
  for (int n = 0; n < 16; ++n) An[n] = -__expf(A_log[d * 16 + n]);
  const short4v* dps = (const short4v*)(dt + (size_t)g * L + c * 32);
  const short4v* ups = (const short4v*)(u  + (size_t)g * L + c * 32);
  const short4v* zps = (const short4v*)(z  + (size_t)g * L + c * 32);
  const short4v* Bs4 = (const short4v*)Bsh;
  const short4v* Cs4 = (const short4v*)Csh;
  float Dd = Dp[d];

  float h[16], pi[16], q[16];
#pragma unroll
  for (int n = 0; n < 16; ++n) { h[n] = 0.f; pi[n] = 1.f; q[n] = 0.f; }
  float base = 0.f;

#pragma unroll 1
  for (int t4 = 0; t4 < 8; ++t4) {
    short4v d4 = dps[t4], u4 = ups[t4], z4 = zps[t4];
#pragma unroll
    for (int i = 0; i < 4; ++i) {
      int step = t4 * 4 + i;
      float dtv = bits2f(d4[i]);
      float uv  = bits2f(u4[i]);
      float zv  = bits2f(z4[i]);
      float sv  = zv / (1.f + __expf(-zv));
      float du  = dtv * uv;
      int slot = step * 32 + c;
      float y0 = 0.f, y1 = 0.f;
#pragma unroll
      for (int n4 = 0; n4 < 4; ++n4) {
        short4v bq = Bs4[n4 * 1024 + slot];
        short4v cq = Cs4[n4 * 1024 + slot];
#pragma unroll
        for (int nn = 0; nn < 4; ++nn) {
          int n = n4 * 4 + nn;
          float a = __expf(dtv * An[n]);
          float Bv = bits2f(bq[nn]);
          float Cv = bits2f(cq[nn]);
          h[n] = fmaf(a, h[n], du * Bv);
          pi[n] *= a;
          if (nn & 1) y1 = fmaf(h[n], Cv, y1); else y0 = fmaf(h[n], Cv, y0);
          q[n] = fmaf(sv * pi[n], Cv, q[n]);
        }
      }
      base = fmaf(sv, (y0 + y1) + uv * Dd, base);
    }
  }

#pragma unroll
  for (int s = 1; s < 32; s <<= 1) {
    bool act = (c >= s);
#pragma unroll
    for (int n = 0; n < 16; ++n) {
      float Po = __shfl_up(pi[n], (unsigned)s, 32);
      float Oo = __shfl_up(h[n], (unsigned)s, 32);
      if (act) { h[n] = fmaf(pi[n], Oo, h[n]); pi[n] *= Po; }
    }
  }
  float pooled = base;
#pragma unroll
  for (int n = 0; n < 16; ++n) {
    float v = __shfl_up(h[n], 1u, 32);
    float hin = (c == 0) ? 0.f : v;
    pooled = fmaf(q[n], hin, pooled);
  }
#pragma unroll
  for (int s = 1; s < 32; s <<= 1) pooled += __shfl_xor(pooled, s, 32);
  if (c == 0) pooled64[g] = pooled;
}

// ---- k_fc: out_proj(mean) + fc ----
__global__ __launch_bounds__(128) void k_fc(
    const float* __restrict__ pooled64, const float* __restrict__ opw,
    const float* __restrict__ fcw, const float* __restrict__ fcb,
    float* __restrict__ out) {
  __shared__ float p64[64];
  __shared__ float o32[32];
  int b = blockIdx.x, t = threadIdx.x;
  if (t < 64) p64[t] = pooled64[b * 64 + t];
  __syncthreads();
  if (t < 32) {
    float s = 0.f;
#pragma unroll
    for (int d0 = 0; d0 < 64; ++d0) s = fmaf(p64[d0], opw[t * 64 + d0], s);
    o32[t] = s * (1.f / 1024.f);
  }
  __syncthreads();
  float acc = fcb[t];
#pragma unroll
  for (int j = 0; j < 32; ++j) acc = fmaf(o32[j], fcw[t * 32 + j], acc);
  out[b * 128 + t] = acc;
}

extern "C" void kernel_launch(void* const* d_in, const int* in_sizes, int n_in,
                              void* d_out, int out_size, void* d_ws, size_t ws_size,
                              hipStream_t stream) {
  const float* x      = (const float*)d_in[0];
  const float* conv_w = (const float*)d_in[1];
  const float* conv_b = (const float*)d_in[2];
  const float* bn_g   = (const float*)d_in[3];
  const float* bn_b   = (const float*)d_in[4];
  const float* bn_m   = (const float*)d_in[5];
  const float* bn_v   = (const float*)d_in[6];
  const float* ipw    = (const float*)d_in[7];
  const float* c1w    = (const float*)d_in[8];
  const float* c1b    = (const float*)d_in[9];
  const float* xpw    = (const float*)d_in[10];
  const float* dtw    = (const float*)d_in[11];
  const float* dtbp   = (const float*)d_in[12];
  const float* A_log  = (const float*)d_in[13];
  const float* Dp     = (const float*)d_in[14];
  const float* opw    = (const float*)d_in[15];
  const float* fcw    = (const float*)d_in[16];
  const float* fcb    = (const float*)d_in[17];

  char* ws = (char*)d_ws;
  bf* xmb = (bf*)(ws + 0);               // 8 MB (b,l,d)
  bf* zb  = (bf*)(ws + 8388608);         // 8 MB (b,d,l)
  bf* ub  = (bf*)(ws + 16777216);        // 8 MB (b,d,l)
  bf* dtb = (bf*)(ws + 25165824);        // 8 MB (b,d,l)
  bf* Btb = (bf*)(ws + 33554432);        // 2 MB (quad-permuted)
  bf* Ctb = (bf*)(ws + 35651584);        // 2 MB (quad-permuted)
  float* pooled = (float*)(ws + 37748736); // 16 KB

  hipLaunchKernelGGL(k_front, dim3(1024), dim3(256), 0, stream,
                     x, conv_w, conv_b, bn_g, bn_b, bn_m, bn_v, ipw, xmb, zb);
  hipLaunchKernelGGL(k_mid, dim3(1024), dim3(256), 0, stream,
                     xmb, c1w, c1b, xpw, dtw, dtbp, ub, dtb, Btb, Ctb);
  hipLaunchKernelGGL(k_scan, dim3(512), dim3(256), 0, stream,
                     ub, dtb, zb, Btb, Ctb, A_log, Dp, pooled);
  hipLaunchKernelGGL(k_fc, dim3(64), dim3(128), 0, stream,
                     pooled, opw, fcw, fcb, (float*)d_out);
}

// Round 21
// 109.600 us; speedup vs baseline: 1.1887x; 1.1887x over previous
//
#include <hip/hip_runtime.h>
#include <hip/hip_bf16.h>
#include <math.h>

#define L 1024
typedef __hip_bfloat16 bf;
typedef __attribute__((ext_vector_type(8))) short short8v;
typedef __attribute__((ext_vector_type(4))) short short4v;

__device__ __forceinline__ float b2f(bf v) { return __bfloat162float(v); }
__device__ __forceinline__ bf f2b(float v) { return __float2bfloat16(v); }
__device__ __forceinline__ float bits2f(short s) {
  union { unsigned u; float f; } cv; cv.u = ((unsigned)(unsigned short)s) << 16; return cv.f;
}
union Pack4 { short4v v; unsigned short e[4]; };
union Pack8 { short8v v; unsigned short e[8]; };
__device__ __forceinline__ unsigned short f2bits(float v) {
  union { bf b; unsigned short u; } cv; cv.b = __float2bfloat16(v); return cv.u;
}

// ---- k_front: LDS x-tile + split conv (wave q: 8 d's) + in_proj quarters ---
__global__ __launch_bounds__(256, 2) void k_front(
    const float* __restrict__ x, const float* __restrict__ conv_w,
    const float* __restrict__ conv_b, const float* __restrict__ gamma,
    const float* __restrict__ beta, const float* __restrict__ mean,
    const float* __restrict__ var, const float* __restrict__ ipw,
    bf* __restrict__ xm, bf* __restrict__ z) {
  __shared__ float xs[64 * 65];    // 16.25 KB x-tile [c][l_local]
  __shared__ float hsh[64][34];    // 8.7 KB
  int t = threadIdx.x;
  int b = blockIdx.x >> 4;         // grid 1024 = 64 b x 16 ltiles
  int l0 = (blockIdx.x & 15) << 6;
  const float* xg = x + (size_t)b * 65536 + l0;
#pragma unroll
  for (int k = 0; k < 16; ++k) {
    int i = t + k * 256;           // [0,4096)
    int c = i >> 6, ll = i & 63;
    xs[c * 65 + ll] = xg[(size_t)c * L + ll];   // 1KB contiguous per wave
  }
  __syncthreads();
  int lq = t & 63;
  int q = __builtin_amdgcn_readfirstlane(t >> 6);  // wave idx, FORCED SGPR
  int l = l0 | lq;
  float hacc[8];
#pragma unroll
  for (int dd = 0; dd < 8; ++dd) hacc[dd] = conv_b[q * 8 + dd];
#pragma unroll
  for (int c4 = 0; c4 < 16; ++c4) {
    float x0 = xs[(c4 * 4 + 0) * 65 + lq];
    float x1 = xs[(c4 * 4 + 1) * 65 + lq];
    float x2 = xs[(c4 * 4 + 2) * 65 + lq];
    float x3 = xs[(c4 * 4 + 3) * 65 + lq];
#pragma unroll
    for (int dd = 0; dd < 8; ++dd) {
      const float* w = conv_w + (q * 8 + dd) * 64 + c4 * 4;  // s_load (uniform)
      hacc[dd] = fmaf(x0, w[0], fmaf(x1, w[1],
                 fmaf(x2, w[2], fmaf(x3, w[3], hacc[dd]))));
    }
  }
#pragma unroll
  for (int dd = 0; dd < 8; ++dd) {
    int d = q * 8 + dd;
    float sc = gamma[d] * rsqrtf(var[d] + 1e-5f);
    float acc = (hacc[dd] - mean[d]) * sc + beta[d];
    hsh[lq][d] = 0.5f * acc * (1.0f + erff(acc * 0.70710678118654752f));
  }
  __syncthreads();
  float h[32];
#pragma unroll
  for (int d = 0; d < 32; ++d) h[d] = hsh[lq][d];
  if (q < 2) {
    short8v* xr8 = (short8v*)(xm + ((size_t)b * 1024 + l) * 64) + q * 4;
#pragma unroll
    for (int j8 = 0; j8 < 4; ++j8) {
      Pack8 p;
#pragma unroll
      for (int e = 0; e < 8; ++e) {
        int j = q * 32 + j8 * 8 + e;
        float acc = 0.f;
#pragma unroll
        for (int d = 0; d < 32; ++d) acc = fmaf(h[d], ipw[j * 32 + d], acc);
        p.e[e] = f2bits(acc);
      }
      xr8[j8] = p.v;
    }
  } else {
    bf* zp = z + (size_t)b * 65536 + l;
#pragma unroll
    for (int jj = 0; jj < 32; ++jj) {
      int j = (q - 2) * 32 + jj;
      float acc = 0.f;
#pragma unroll
      for (int d = 0; d < 32; ++d) acc = fmaf(h[d], ipw[(j + 64) * 32 + d], acc);
      zp[(size_t)j * L] = f2b(acc);
    }
  }
}

// ---- k_mid v3: xm-tile + xpw in LDS; balanced 3-phase wave split ----
// P1: wave q conv+silu 16 d's (LDS xm reads). P2: 34 x_proj dots split
// 9/9/8/8 with broadcast-LDS weights -> xdh. P3: dt 16/wave + B/C quad/wave.
__global__ __launch_bounds__(256, 2) void k_mid(
    const bf* __restrict__ xm, const float* __restrict__ c1w,
    const float* __restrict__ c1b, const float* __restrict__ xpw,
    const float* __restrict__ dtw, const float* __restrict__ dtbp,
    bf* __restrict__ u, bf* __restrict__ dt_o,
    bf* __restrict__ Bt, bf* __restrict__ Ct) {
  __shared__ bf    xsh[67 * 68];   // 9.1 KB  xm rows [l0-3, l0+64), stride 68
  __shared__ float wsh[34 * 64];   // 8.5 KB  xpw
  __shared__ float ush[64 * 65];   // 16.6 KB silu(conv1d) [l][d]
  __shared__ float xdh[64 * 35];   // 8.96 KB x_dbl [l][k]
  int t = threadIdx.x;
  int lq = t & 63;
  int q = __builtin_amdgcn_readfirstlane(t >> 6);   // wave idx, SGPR
  int b = blockIdx.x >> 4;         // grid 1024 = 64 b x 16 ltiles
  int l0 = (blockIdx.x & 15) << 6;
  int l = l0 | lq;
  // stage xm tile (contiguous global region) + xpw
  {
    const short4v* xg4 = (const short4v*)(xm + ((size_t)b * 1024 + l0 - 3) * 64);
    for (int i = t; i < 1072; i += 256) {       // 67 rows x 16 short4
      int r = i >> 4, c4 = i & 15;
      short4v v;
      if (l0 == 0 && r < 3) { v[0] = v[1] = v[2] = v[3] = 0; }
      else v = xg4[i];                          // linear: i*8 bytes
      *(short4v*)(&xsh[r * 68 + c4 * 4]) = v;
    }
    const float4* wg = (const float4*)xpw;
    float4* ws4 = (float4*)wsh;
    for (int i = t; i < 544; i += 256) ws4[i] = wg[i];
  }
  __syncthreads();
  // P1: conv1d + silu for d in [16q, 16q+16)
  float um[16];
#pragma unroll
  for (int dd = 0; dd < 16; ++dd) um[dd] = c1b[q * 16 + dd];
#pragma unroll
  for (int k = 0; k < 4; ++k) {
    const short4v* xr = (const short4v*)(&xsh[(lq + k) * 68 + q * 16]);
#pragma unroll
    for (int c4 = 0; c4 < 4; ++c4) {
      short4v v = xr[c4];                       // ds_read_b64, 4-way max
#pragma unroll
      for (int e = 0; e < 4; ++e)
        um[c4 * 4 + e] = fmaf(c1w[(q * 16 + c4 * 4 + e) * 4 + k],
                              bits2f(v[e]), um[c4 * 4 + e]);
    }
  }
  {
    bf* up = u + (size_t)b * 65536 + l;
#pragma unroll
    for (int dd = 0; dd < 16; ++dd) {
      float s = um[dd];
      s = s / (1.f + __expf(-s));               // silu
      ush[lq * 65 + q * 16 + dd] = s;
      up[(size_t)(q * 16 + dd) * L] = f2b(s);   // coalesced col stores
    }
  }
  __syncthreads();
  // P2: x_proj dots, waves own k-ranges 9/9/8/8; weights broadcast from LDS
  {
    float um64[64];
#pragma unroll
    for (int d = 0; d < 64; ++d) um64[d] = ush[lq * 65 + d];  // 2-way, free
    int k0 = (q < 2) ? q * 9 : 18 + (q - 2) * 8;
    int nk = (q < 2) ? 9 : 8;
    for (int kk = 0; kk < nk; ++kk) {
      int k = k0 + kk;                          // uniform (SGPR)
      const float4* wr = (const float4*)(&wsh[k * 64]);
      float acc = 0.f;
#pragma unroll
      for (int d4 = 0; d4 < 16; ++d4) {
        float4 w4 = wr[d4];                     // broadcast ds_read_b128
        acc = fmaf(um64[d4 * 4 + 0], w4.x, fmaf(um64[d4 * 4 + 1], w4.y,
              fmaf(um64[d4 * 4 + 2], w4.z, fmaf(um64[d4 * 4 + 3], w4.w, acc))));
      }
      xdh[lq * 35 + k] = acc;
    }
  }
  __syncthreads();
  // P3: dt for 16 d's per wave + one B-quad + one C-quad per wave
  {
    float xd0 = xdh[lq * 35 + 0], xd1 = xdh[lq * 35 + 1];
    bf* dp = dt_o + (size_t)b * 65536 + l;
#pragma unroll
    for (int dd = 0; dd < 16; ++dd) {
      int d = q * 16 + dd;                      // uniform -> dtw via s_load
      float raw = fmaf(xd0, dtw[d * 2], fmaf(xd1, dtw[d * 2 + 1], dtbp[d]));
      float sp = fmaxf(raw, 0.f) + log1pf(__expf(-fabsf(raw)));
      dp[(size_t)d * L] = f2b(sp);
    }
    int i = l & 31, c = l >> 5;
    size_t basei = ((size_t)b * 16384 + (size_t)i * 128 + c * 4) >> 2;
    short4v* B4 = (short4v*)Bt;
    short4v* C4 = (short4v*)Ct;
    Pack4 pb, pc;
#pragma unroll
    for (int nn = 0; nn < 4; ++nn) {
      pb.e[nn] = f2bits(xdh[lq * 35 + 2 + q * 4 + nn]);
      pc.e[nn] = f2bits(xdh[lq * 35 + 18 + q * 4 + nn]);
    }
    B4[basei + (size_t)q * 1024] = pb.v;
    C4[basei + (size_t)q * 1024] = pc.v;
  }
}

// ---- k_scan: single-sweep chunked scan, B/C in LDS (b64 quads), gate+pool --
__global__ __launch_bounds__(256, 2) void k_scan(
    const bf* __restrict__ u, const bf* __restrict__ dt,
    const bf* __restrict__ z, const bf* __restrict__ Bt,
    const bf* __restrict__ Ct, const float* __restrict__ A_log,
    const float* __restrict__ Dp, float* __restrict__ pooled64) {
  __shared__ bf Bsh[16384];
  __shared__ bf Csh[16384];
  int phys = blockIdx.x;      // 512 blocks
  int b = phys & 63;
  int dgrp = phys >> 6;
  int t = threadIdx.x;
  int d_local = t >> 5, c = t & 31;
  int d = dgrp * 8 + d_local;
  int g = b * 64 + d;

  {
    const short8v* Bg8 = (const short8v*)(Bt + (size_t)b * 16384);
    const short8v* Cg8 = (const short8v*)(Ct + (size_t)b * 16384);
    short8v* Bs8 = (short8v*)Bsh;
    short8v* Cs8 = (short8v*)Csh;
#pragma unroll
    for (int q = 0; q < 8; ++q) {
      Bs8[t + q * 256] = Bg8[t + q * 256];
      Cs8[t + q * 256] = Cg8[t + q * 256];
    }
  }
  __syncthreads();

  float An[16];
#pragma unroll
  for (int n = 0; n < 16; ++n) An[n] = -__expf(A_log[d * 16 + n]);
  const short4v* dps = (const short4v*)(dt + (size_t)g * L + c * 32);
  const short4v* ups = (const short4v*)(u  + (size_t)g * L + c * 32);
  const short4v* zps = (const short4v*)(z  + (size_t)g * L + c * 32);
  const short4v* Bs4 = (const short4v*)Bsh;
  const short4v* Cs4 = (const short4v*)Csh;
  float Dd = Dp[d];

  float h[16], pi[16], q[16];
#pragma unroll
  for (int n = 0; n < 16; ++n) { h[n] = 0.f; pi[n] = 1.f; q[n] = 0.f; }
  float base = 0.f;

#pragma unroll 1
  for (int t4 = 0; t4 < 8; ++t4) {
    short4v d4 = dps[t4], u4 = ups[t4], z4 = zps[t4];
#pragma unroll
    for (int i = 0; i < 4; ++i) {
      int step = t4 * 4 + i;
      float dtv = bits2f(d4[i]);
      float uv  = bits2f(u4[i]);
      float zv  = bits2f(z4[i]);
      float sv  = zv / (1.f + __expf(-zv));
      float du  = dtv * uv;
      int slot = step * 32 + c;
      float y0 = 0.f, y1 = 0.f;
#pragma unroll
      for (int n4 = 0; n4 < 4; ++n4) {
        short4v bq = Bs4[n4 * 1024 + slot];
        short4v cq = Cs4[n4 * 1024 + slot];
#pragma unroll
        for (int nn = 0; nn < 4; ++nn) {
          int n = n4 * 4 + nn;
          float a = __expf(dtv * An[n]);
          float Bv = bits2f(bq[nn]);
          float Cv = bits2f(cq[nn]);
          h[n] = fmaf(a, h[n], du * Bv);
          pi[n] *= a;
          if (nn & 1) y1 = fmaf(h[n], Cv, y1); else y0 = fmaf(h[n], Cv, y0);
          q[n] = fmaf(sv * pi[n], Cv, q[n]);
        }
      }
      base = fmaf(sv, (y0 + y1) + uv * Dd, base);
    }
  }

#pragma unroll
  for (int s = 1; s < 32; s <<= 1) {
    bool act = (c >= s);
#pragma unroll
    for (int n = 0; n < 16; ++n) {
      float Po = __shfl_up(pi[n], (unsigned)s, 32);
      float Oo = __shfl_up(h[n], (unsigned)s, 32);
      if (act) { h[n] = fmaf(pi[n], Oo, h[n]); pi[n] *= Po; }
    }
  }
  float pooled = base;
#pragma unroll
  for (int n = 0; n < 16; ++n) {
    float v = __shfl_up(h[n], 1u, 32);
    float hin = (c == 0) ? 0.f : v;
    pooled = fmaf(q[n], hin, pooled);
  }
#pragma unroll
  for (int s = 1; s < 32; s <<= 1) pooled += __shfl_xor(pooled, s, 32);
  if (c == 0) pooled64[g] = pooled;
}

// ---- k_fc: out_proj(mean) + fc ----
__global__ __launch_bounds__(128) void k_fc(
    const float* __restrict__ pooled64, const float* __restrict__ opw,
    const float* __restrict__ fcw, const float* __restrict__ fcb,
    float* __restrict__ out) {
  __shared__ float p64[64];
  __shared__ float o32[32];
  int b = blockIdx.x, t = threadIdx.x;
  if (t < 64) p64[t] = pooled64[b * 64 + t];
  __syncthreads();
  if (t < 32) {
    float s = 0.f;
#pragma unroll
    for (int d0 = 0; d0 < 64; ++d0) s = fmaf(p64[d0], opw[t * 64 + d0], s);
    o32[t] = s * (1.f / 1024.f);
  }
  __syncthreads();
  float acc = fcb[t];
#pragma unroll
  for (int j = 0; j < 32; ++j) acc = fmaf(o32[j], fcw[t * 32 + j], acc);
  out[b * 128 + t] = acc;
}

extern "C" void kernel_launch(void* const* d_in, const int* in_sizes, int n_in,
                              void* d_out, int out_size, void* d_ws, size_t ws_size,
                              hipStream_t stream) {
  const float* x      = (const float*)d_in[0];
  const float* conv_w = (const float*)d_in[1];
  const float* conv_b = (const float*)d_in[2];
  const float* bn_g   = (const float*)d_in[3];
  const float* bn_b   = (const float*)d_in[4];
  const float* bn_m   = (const float*)d_in[5];
  const float* bn_v   = (const float*)d_in[6];
  const float* ipw    = (const float*)d_in[7];
  const float* c1w    = (const float*)d_in[8];
  const float* c1b    = (const float*)d_in[9];
  const float* xpw    = (const float*)d_in[10];
  const float* dtw    = (const float*)d_in[11];
  const float* dtbp   = (const float*)d_in[12];
  const float* A_log  = (const float*)d_in[13];
  const float* Dp     = (const float*)d_in[14];
  const float* opw    = (const float*)d_in[15];
  const float* fcw    = (const float*)d_in[16];
  const float* fcb    = (const float*)d_in[17];

  char* ws = (char*)d_ws;
  bf* xmb = (bf*)(ws + 0);               // 8 MB (b,l,d)
  bf* zb  = (bf*)(ws + 8388608);         // 8 MB (b,d,l)
  bf* ub  = (bf*)(ws + 16777216);        // 8 MB (b,d,l)
  bf* dtb = (bf*)(ws + 25165824);        // 8 MB (b,d,l)
  bf* Btb = (bf*)(ws + 33554432);        // 2 MB (quad-permuted)
  bf* Ctb = (bf*)(ws + 35651584);        // 2 MB (quad-permuted)
  float* pooled = (float*)(ws + 37748736); // 16 KB

  hipLaunchKernelGGL(k_front, dim3(1024), dim3(256), 0, stream,
                     x, conv_w, conv_b, bn_g, bn_b, bn_m, bn_v, ipw, xmb, zb);
  hipLaunchKernelGGL(k_mid, dim3(1024), dim3(256), 0, stream,
                     xmb, c1w, c1b, xpw, dtw, dtbp, ub, dtb, Btb, Ctb);
  hipLaunchKernelGGL(k_scan, dim3(512), dim3(256), 0, stream,
                     ub, dtb, zb, Btb, Ctb, A_log, Dp, pooled);
  hipLaunchKernelGGL(k_fc, dim3(64), dim3(128), 0, stream,
                     pooled, opw, fcw, fcb, (float*)d_out);
}